// Round 7
// baseline (423.067 us; speedup 1.0000x reference)
//
#include <hip/hip_runtime.h>
#include <hip/hip_bf16.h>

// WOQ int4-asym (tinygemm) linear: out[64,8192] = x @ dequant(w).T
// dequant: (q - 8)*scale + zp, groups of 128 along K.
//
// R9: REPACK + L3-RESIDENT GEMM. Evidence: R6/R7/R8 (scatter / 512B /
// 2KB-linear weight streams) all land 110-140us ~ 2.3 TB/s -> the wall is
// the depth-1 staged pipeline's duty cycle, not the DRAM pattern. Rather
// than build a counted-vmcnt deep pipeline, change the data: weights are
// int32 per 4-bit value (256MB for 32MB of info).
//   1) repack: pure streaming kernel (the regime where the harness's own
//      fill hits 6.7 TB/s): each lane reads int4 (1KB linear/wave instr),
//      emits ushort of 4 nibbles into d_ws (32 MiB; the 1-GiB ws poison
//      runs unconditionally, so ws use is free).  ~50us.
//   2) gemm<PACKED>: R6's PROVEN structure (LDS-staged x dbuf, 1 barrier
//      per group, zero_out + atomicAdd epilogue) with the weight load
//      shrunk to ONE dword per lane per ks (8 nibbles). 32MB packed is
//      L3-resident -> the gemm's HBM wait vanishes.  ~30us.
// Fallback if ws too small: gemm<false> = R6's unpacked path verbatim.

#define OUT_F 8192
#define IN_F  8192
#define M_TOK 64
#define GROUP 128
#define BN    64
#define KSPLIT 8
#define KR    (IN_F / KSPLIT)   // 1024 k per block
#define GROUPS (KR / GROUP)     // 8
#define PACK_BYTES ((size_t)OUT_F * IN_F / 2)   // 32 MiB

typedef short short8 __attribute__((ext_vector_type(8)));
typedef float f32x4  __attribute__((ext_vector_type(4)));
typedef unsigned u32x4 __attribute__((ext_vector_type(4)));

// pack two fp32 -> packed bf16 pair (RNE, v_cvt_pk_bf16_f32)
__device__ __forceinline__ unsigned pk(float lo, float hi) {
    __hip_bfloat162 h = __float22bfloat162_rn(float2{lo, hi});
    unsigned r;
    __builtin_memcpy(&r, &h, sizeof(r));
    return r;
}

__global__ void zero_out(float* __restrict__ p) {
    const int i = (blockIdx.x * 256 + threadIdx.x) * 4;
    *(float4*)(p + i) = float4{0.f, 0.f, 0.f, 0.f};
}

// int32 weights [0,15] -> nibble stream. ushort i covers ints 4i..4i+4;
// dword i of the packed array = nibbles for k = 8i..8i+8 (little-endian).
__global__ __launch_bounds__(256)
void repack(const int* __restrict__ qw, unsigned short* __restrict__ pw) {
    const size_t nth = (size_t)gridDim.x * 256;
    const int4* q4 = (const int4*)qw;
    for (size_t i = (size_t)blockIdx.x * 256 + threadIdx.x;
         i < (size_t)OUT_F * IN_F / 4; i += nth) {
        const int4 a = q4[i];               // 1 KB linear per wave instr
        pw[i] = (unsigned short)((a.x & 15) | ((a.y & 15) << 4) |
                                 ((a.z & 15) << 8) | ((a.w & 15) << 12));
    }
}

template <bool PACKED>
__global__ __launch_bounds__(256, 4)
void woq_gemm(const float* __restrict__ x,
              const int*   __restrict__ qw,
              const unsigned* __restrict__ pw,
              const float* __restrict__ sz,
              float*       __restrict__ outp) {
    // two 16 KB bf16 x-tiles, frag order: slot=(ks*4+mi)*64+lane,
    // lane l holds x[mi*16+(l&15)][ks*32+(l>>4)*8 .. +8]
    __shared__ int lds_x[2][1024 * 4];

    const int t    = threadIdx.x;
    const int lane = t & 63;
    const int wv   = t >> 6;          // wave 0..3 -> n-offset wv*16
    const int n0   = blockIdx.x * BN;
    const int k0   = blockIdx.y * KR;

    const int nlo  = lane & 15;
    const int quad = lane >> 4;
    const int kq8  = quad << 3;

    const int n1 = n0 + wv * 16 + nlo;            // this lane's n column
    const int*      qr  = qw + (size_t)n1 * IN_F;         // unpacked row
    const unsigned* pwr = pw + (size_t)n1 * (IN_F / 8);   // packed row

    f32x4 acc[4];
#pragma unroll
    for (int mi = 0; mi < 4; ++mi) acc[mi] = (f32x4){0.f, 0.f, 0.f, 0.f};

    float4 xs[8];   // staging registers for the next group's x tile

    // ---- prologue: load + store x stage for g=0 ----
#pragma unroll
    for (int i = 0; i < 4; ++i) {
        const int slot  = t + 256 * i;
        const int chunk = slot >> 6;
        const int l     = slot & 63;
        const int m     = ((chunk & 3) << 4) + (l & 15);
        const int kk    = ((chunk >> 2) << 5) + ((l >> 4) << 3);
        const float4* p = (const float4*)(x + (size_t)m * IN_F + k0 + kk);
        xs[2 * i]     = p[0];
        xs[2 * i + 1] = p[1];
    }
#pragma unroll
    for (int i = 0; i < 4; ++i) {
        const int slot = t + 256 * i;
        u32x4 bv;
        bv.x = pk(xs[2 * i].x,     xs[2 * i].y);
        bv.y = pk(xs[2 * i].z,     xs[2 * i].w);
        bv.z = pk(xs[2 * i + 1].x, xs[2 * i + 1].y);
        bv.w = pk(xs[2 * i + 1].z, xs[2 * i + 1].w);
        *(u32x4*)&lds_x[0][slot * 4] = bv;
    }
    __syncthreads();

    for (int g = 0; g < GROUPS; ++g) {
        const int kg = k0 + g * GROUP;

        // 1) issue global x loads for group g+1
        if (g + 1 < GROUPS) {
#pragma unroll
            for (int i = 0; i < 4; ++i) {
                const int slot  = t + 256 * i;
                const int chunk = slot >> 6;
                const int l     = slot & 63;
                const int m     = ((chunk & 3) << 4) + (l & 15);
                const int kk    = ((chunk >> 2) << 5) + ((l >> 4) << 3);
                const float4* p = (const float4*)(x + (size_t)m * IN_F + kg + GROUP + kk);
                xs[2 * i]     = p[0];
                xs[2 * i + 1] = p[1];
            }
        }

        // 2) compute group g from lds buffer g&1
        const int gg = kg >> 7;
        const float2 ps = *(const float2*)(sz + ((size_t)gg * OUT_F + n1) * 2);
        const float s1 = ps.x, c1 = fmaf(-8.f, ps.x, ps.y);
        const int* bufp = lds_x[g & 1];

#pragma unroll
        for (int ks = 0; ks < 4; ++ks) {
            short8 a[4];
#pragma unroll
            for (int mi = 0; mi < 4; ++mi)
                a[mi] = *(const short8*)&bufp[((ks * 4 + mi) * 64 + lane) * 4];

            u32x4 bi;
            if constexpr (PACKED) {
                const unsigned wb = pwr[(kg + ks * 32 + kq8) >> 3];   // 8 nibbles
                bi.x = pk(fmaf((float)( wb        & 15u), s1, c1),
                          fmaf((float)((wb >>  4) & 15u), s1, c1));
                bi.y = pk(fmaf((float)((wb >>  8) & 15u), s1, c1),
                          fmaf((float)((wb >> 12) & 15u), s1, c1));
                bi.z = pk(fmaf((float)((wb >> 16) & 15u), s1, c1),
                          fmaf((float)((wb >> 20) & 15u), s1, c1));
                bi.w = pk(fmaf((float)((wb >> 24) & 15u), s1, c1),
                          fmaf((float)( wb >> 28       ), s1, c1));
            } else {
                const int* qp = qr + kg + ks * 32 + kq8;
                const int4 qa = *(const int4*)(qp);
                const int4 qb = *(const int4*)(qp + 4);
                bi.x = pk(fmaf((float)qa.x, s1, c1), fmaf((float)qa.y, s1, c1));
                bi.y = pk(fmaf((float)qa.z, s1, c1), fmaf((float)qa.w, s1, c1));
                bi.z = pk(fmaf((float)qb.x, s1, c1), fmaf((float)qb.y, s1, c1));
                bi.w = pk(fmaf((float)qb.z, s1, c1), fmaf((float)qb.w, s1, c1));
            }
            const short8 b = __builtin_bit_cast(short8, bi);

#pragma unroll
            for (int mi = 0; mi < 4; ++mi)
                acc[mi] = __builtin_amdgcn_mfma_f32_16x16x32_bf16(a[mi], b, acc[mi], 0, 0, 0);
        }

        // 3) pack + write x stage for g+1 into the other buffer
        if (g + 1 < GROUPS) {
            int* dstb = lds_x[(g + 1) & 1];
#pragma unroll
            for (int i = 0; i < 4; ++i) {
                const int slot = t + 256 * i;
                u32x4 bv;
                bv.x = pk(xs[2 * i].x,     xs[2 * i].y);
                bv.y = pk(xs[2 * i].z,     xs[2 * i].w);
                bv.z = pk(xs[2 * i + 1].x, xs[2 * i + 1].y);
                bv.w = pk(xs[2 * i + 1].z, xs[2 * i + 1].w);
                *(u32x4*)&dstb[slot * 4] = bv;
            }
            __syncthreads();   // one barrier per group
        }
    }

    // ---- epilogue: atomic accumulate into pre-zeroed output ----
    // C/D layout: col = lane&15 (n), row = quad*4 + r (m within frag)
#pragma unroll
    for (int mi = 0; mi < 4; ++mi) {
#pragma unroll
        for (int r = 0; r < 4; ++r) {
            const int m = mi * 16 + quad * 4 + r;
            atomicAdd(outp + (size_t)m * OUT_F + n1, acc[mi][r]);
        }
    }
}

extern "C" void kernel_launch(void* const* d_in, const int* in_sizes, int n_in,
                              void* d_out, int out_size, void* d_ws, size_t ws_size,
                              hipStream_t stream) {
    const float* x  = (const float*)d_in[0];
    const int*   qw = (const int*)d_in[1];
    const float* sz = (const float*)d_in[2];
    float* out = (float*)d_out;

    zero_out<<<dim3((M_TOK * OUT_F) / (256 * 4)), 256, 0, stream>>>(out);

    if (ws_size >= PACK_BYTES) {
        unsigned short* pw = (unsigned short*)d_ws;
        repack<<<dim3(2048), 256, 0, stream>>>(qw, pw);
        woq_gemm<true><<<dim3(OUT_F / BN, KSPLIT), 256, 0, stream>>>(
            x, qw, (const unsigned*)pw, sz, out);
    } else {
        woq_gemm<false><<<dim3(OUT_F / BN, KSPLIT), 256, 0, stream>>>(
            x, qw, nullptr, sz, out);
    }
}

// Round 8
// 366.414 us; speedup vs baseline: 1.1546x; 1.1546x over previous
//
#include <hip/hip_runtime.h>
#include <hip/hip_bf16.h>

// WOQ int4-asym (tinygemm) linear: out[64,8192] = x @ dequant(w).T
// dequant: (q - 8)*scale + zp, groups of 128 along K.
//
// R10 = R7 (best structure, kernels ~113us) + NON-TEMPORAL weight loads.
// Theory: the harness's unconditional 1-GiB d_ws poison fill leaves the
// 256MiB LLC 100% dirty every iteration; allocating weight reads must
// evict+write-back a dirty line per miss -> ~256MB hidden writeback +
// r/w turnaround -> the constant ~2.4 TB/s wall seen across R6/R7/R8/R9
// regardless of access pattern. nt loads bypass LLC allocation -> no
// eviction storm -> pure 256MB DRAM read stream.
// Everything else is R7 verbatim: coalesced weight staging (1KB linear
// per wave instr), dequant-on-stage to XOR-swizzled bf16 LDS, compute
// phase pure LDS+MFMA (lgkm-only), BN=64/KSPLIT=4/512thr/2 blocks/CU,
// one barrier per group, kh-pair LDS reduce + atomicAdd epilogue.

#define OUT_F 8192
#define IN_F  8192
#define M_TOK 64
#define GROUP 128
#define BN    64
#define KSPLIT 4
#define KR    (IN_F / KSPLIT)   // 2048 k per block
#define GROUPS (KR / GROUP)     // 16

typedef short short8 __attribute__((ext_vector_type(8)));
typedef float f32x4  __attribute__((ext_vector_type(4)));
typedef int   int4v  __attribute__((ext_vector_type(4)));

// pack two fp32 -> packed bf16 pair (RNE, v_cvt_pk_bf16_f32)
__device__ __forceinline__ unsigned pk(float lo, float hi) {
    __hip_bfloat162 h = __float22bfloat162_rn(float2{lo, hi});
    unsigned r;
    __builtin_memcpy(&r, &h, sizeof(r));
    return r;
}

__global__ void zero_out(float* __restrict__ p) {
    const int i = (blockIdx.x * 256 + threadIdx.x) * 4;
    *(float4*)(p + i) = float4{0.f, 0.f, 0.f, 0.f};
}

__global__ __launch_bounds__(512, 4)
void woq_gemm(const float* __restrict__ x,
              const int*   __restrict__ qw,
              const float* __restrict__ sz,
              float*       __restrict__ outp) {
    // x tiles (bf16, MFMA frag order, dbuf): 2 x 16 KB
    //   slot = (ks*4+mi)*64 + lane; lane l holds x[mi*16+(l&15)][ks*32+(l>>4)*8..+8]
    // w tiles (bf16 [64 rows][128 k], XOR-swizzled, dbuf): 2 x 16 KB
    __shared__ int lds_x[2][4096];
    __shared__ int lds_w[2][4096];

    const int t    = threadIdx.x;       // 0..511
    const int lane = t & 63;
    const int wv   = t >> 6;            // 0..7
    const int wn   = wv & 3;            // n subtile (16 cols)
    const int kh   = wv >> 2;           // k half of each 128-group
    const int n0   = blockIdx.x * BN;
    const int k0   = blockIdx.y * KR;

    const int nlo  = lane & 15;
    const int quad = lane >> 4;
    const int row  = wn * 16 + nlo;     // tile row (n) this lane consumes
    const int n1   = n0 + row;

    // staging identities: chunk c = i*512 + t; row = c>>5 = i*16+tr; 16B col = kc
    const int tr = t >> 5;              // 0..15
    const int kc = t & 31;              // 0..31

    f32x4 acc[4];
#pragma unroll
    for (int mi = 0; mi < 4; ++mi) acc[mi] = (f32x4){0.f, 0.f, 0.f, 0.f};

    int4v  wq[4];    // staged weights (4 rows, 16 B each, contiguous-in-row)
    float2 sc[4];    // scales for those rows
    float4 xs[4];    // staged x (2 slots x 32 B)

    auto stage_load = [&](int g) {
        const int kg = k0 + g * GROUP;
        // weights: per instr i, wave reads two full 512B row-chunks linearly.
        // NON-TEMPORAL: bypass LLC allocation (poison fill leaves LLC dirty;
        // allocating reads pay a dirty-evict writeback per miss).
#pragma unroll
        for (int i = 0; i < 4; ++i) {
            const int r = i * 16 + tr;
            wq[i] = __builtin_nontemporal_load(
                (const int4v*)(qw + (size_t)(n0 + r) * IN_F + kg + kc * 4));
        }
        const int gg = kg >> 7;
#pragma unroll
        for (int i = 0; i < 4; ++i) {
            const int r = i * 16 + tr;
            sc[i] = *(const float2*)(sz + ((size_t)gg * OUT_F + n0 + r) * 2);
        }
        // x tile (L2-resident, keep allocating loads for cross-block reuse)
#pragma unroll
        for (int j = 0; j < 2; ++j) {
            const int slot  = t + 512 * j;
            const int chunk = slot >> 6;
            const int l     = slot & 63;
            const int m     = ((chunk & 3) << 4) + (l & 15);
            const int kk    = ((chunk >> 2) << 5) + ((l >> 4) << 3);
            const float4* p = (const float4*)(x + (size_t)m * IN_F + kg + kk);
            xs[2 * j]     = p[0];
            xs[2 * j + 1] = p[1];
        }
    };

    auto stage_write = [&](int buf) {
        int* wb = lds_w[buf];
#pragma unroll
        for (int i = 0; i < 4; ++i) {
            const int r = i * 16 + tr;
            const float s = sc[i].x;
            const float c = fmaf(-8.f, sc[i].x, sc[i].y);
            int2 v;
            v.x = (int)pk(fmaf((float)wq[i].x, s, c), fmaf((float)wq[i].y, s, c));
            v.y = (int)pk(fmaf((float)wq[i].z, s, c), fmaf((float)wq[i].w, s, c));
            const int idx = (r * 64 + kc * 2) ^ ((r & 7) << 2);   // XOR swizzle
            *(int2*)&wb[idx] = v;
        }
        int* xb = lds_x[buf];
#pragma unroll
        for (int j = 0; j < 2; ++j) {
            const int slot = t + 512 * j;
            int4v bv;
            bv.x = (int)pk(xs[2 * j].x,     xs[2 * j].y);
            bv.y = (int)pk(xs[2 * j].z,     xs[2 * j].w);
            bv.z = (int)pk(xs[2 * j + 1].x, xs[2 * j + 1].y);
            bv.w = (int)pk(xs[2 * j + 1].z, xs[2 * j + 1].w);
            *(int4v*)&xb[slot * 4] = bv;
        }
    };

    // prologue: stage group 0
    stage_load(0);
    stage_write(0);
    __syncthreads();

    for (int g = 0; g < GROUPS; ++g) {
        if (g + 1 < GROUPS) stage_load(g + 1);   // global loads fly over compute

        // compute group g: pure LDS + MFMA (no vmcnt dependence)
        const int* xb = lds_x[g & 1];
        const int* wb = lds_w[g & 1];
#pragma unroll
        for (int s = 0; s < 2; ++s) {
            const int ks = kh * 2 + s;
            const int bidx = (row * 64 + ks * 16 + quad * 4) ^ ((row & 7) << 2);
            const short8 b = *(const short8*)&wb[bidx];
            short8 a[4];
#pragma unroll
            for (int mi = 0; mi < 4; ++mi)
                a[mi] = *(const short8*)&xb[((ks * 4 + mi) * 64 + lane) * 4];
#pragma unroll
            for (int mi = 0; mi < 4; ++mi)
                acc[mi] = __builtin_amdgcn_mfma_f32_16x16x32_bf16(a[mi], b, acc[mi], 0, 0, 0);
        }

        if (g + 1 < GROUPS) {
            stage_write((g + 1) & 1);            // waits vmcnt, writes other buf
            __syncthreads();                     // one barrier per group
        }
    }

    // ---- epilogue: kh-pair reduce via LDS, then atomics ----
    __syncthreads();
    f32x4* redp = (f32x4*)&lds_x[0][0];          // 16 KB scratch (safe: last
    if (kh == 1) {                               // compute used lds_x[1])
#pragma unroll
        for (int mi = 0; mi < 4; ++mi)
            redp[(wn * 4 + mi) * 64 + lane] = acc[mi];
    }
    __syncthreads();
    if (kh == 0) {
#pragma unroll
        for (int mi = 0; mi < 4; ++mi)
            acc[mi] += redp[(wn * 4 + mi) * 64 + lane];
        // C/D layout: col = lane&15 (n), row = quad*4 + r (m within frag)
#pragma unroll
        for (int mi = 0; mi < 4; ++mi)
#pragma unroll
            for (int r = 0; r < 4; ++r)
                atomicAdd(outp + (size_t)(mi * 16 + quad * 4 + r) * OUT_F + n1, acc[mi][r]);
    }
}

extern "C" void kernel_launch(void* const* d_in, const int* in_sizes, int n_in,
                              void* d_out, int out_size, void* d_ws, size_t ws_size,
                              hipStream_t stream) {
    const float* x  = (const float*)d_in[0];
    const int*   qw = (const int*)d_in[1];
    const float* sz = (const float*)d_in[2];
    float* out = (float*)d_out;

    zero_out<<<dim3((M_TOK * OUT_F) / (256 * 4)), 256, 0, stream>>>(out);
    woq_gemm<<<dim3(OUT_F / BN, KSPLIT), 512, 0, stream>>>(x, qw, sz, out);
}